// Round 2
// baseline (132.412 us; speedup 1.0000x reference)
//
#include <hip/hip_runtime.h>
#include <math.h>

#define BB 8
#define TT 2048
#define VV 10
#define HH 5

// One wave (64 lanes) per (b,t) row. Each lane scans 32 s-positions, keeping a
// running f64 argmax of the attention score for each of the 5 heads; shuffle
// reduction, then elementwise epilogue (attention update + MLP + decode).
//
// score(b,h,t,s) = (qk^2/sqrt(2)) * x0[b,t] * x0[b,s] * cos(t-s-off_h)
//                  - 10000*[s>t]
// Softmax over these ~4.6e10-magnitude scores is one-hot in f64 (top-2 gaps
// are ~1e5 absolute; exp(-gap)=0), so att_h = d[b, argmax]. All score math in
// f64 mirrors the np(f64) comparison reference: x0 computed in f64 from the
// f64-promoted f32 eps; q/k cos-sin product form identical to the reference.
__global__ __launch_bounds__(256) void transformer_kernel(
    const int* __restrict__ ids,
    const float* __restrict__ o_w,
    const float* __restrict__ w1_abc,
    const float* __restrict__ w2_s,
    const float* __restrict__ embed_const,
    const float* __restrict__ decode_eps,
    const float* __restrict__ qk_scale,
    const float* __restrict__ rope_offsets,
    float* __restrict__ out)   // reference output dtype is float32
{
    const int wave = threadIdx.x >> 6;
    const int lane = threadIdx.x & 63;
    const int gw = blockIdx.x * 4 + wave;      // global row id in [0, B*T)
    const int b = gw >> 11;                    // / 2048
    const int t = gw & 2047;

    const float Cf   = embed_const[0];
    const float epsf = decode_eps[0];
    const float qkf  = qk_scale[0];

    const double C    = (double)Cf;
    const double quad = 0.5 * (double)epsf;    // matches f64-promoted ref

    const int* idb = ids + b * TT;

    // K = qk^2/sqrt(2) * x0[b,t], all f64
    const double dt_d = (double)idb[t];
    const double x0t  = C - quad * dt_d * dt_d;
    const double K = (double)qkf * (double)qkf * 0.70710678118654752440 * x0t;

    // per-head query direction: K*[cos(t-off), sin(t-off)]
    double Ch[HH], Sh[HH];
    #pragma unroll
    for (int h = 0; h < HH; h++) {
        double arg = (double)t - (double)rope_offsets[h];
        Ch[h] = K * cos(arg);
        Sh[h] = K * sin(arg);
    }

    // per-lane rotating (cos s, sin s), s = i*64 + lane
    double cs = cos((double)lane);
    double sn = sin((double)lane);
    const double c64 = cos(64.0);
    const double s64 = sin(64.0);

    double best[HH];
    float  bd[HH];
    #pragma unroll
    for (int h = 0; h < HH; h++) { best[h] = -1e300; bd[h] = 0.0f; }

    for (int i = 0; i < TT / 64; i++) {
        const int s = i * 64 + lane;
        const double ds = (double)idb[s];
        const double x0s = C - quad * ds * ds;      // f64, mirrors np ref
        const double us = x0s * cs;
        const double vs = x0s * sn;
        const double mask = (s > t) ? -10000.0 : 0.0;
        #pragma unroll
        for (int h = 0; h < HH; h++) {
            const double sc = fma(Ch[h], us, fma(Sh[h], vs, mask));
            if (sc > best[h]) { best[h] = sc; bd[h] = (float)ds; }
        }
        // rotate angle by +64 rad (drift ~1e-15 rel over 32 steps; decision
        // margins are ~1e5 absolute on a 4.6e10 scale -> no flips)
        const double ncs = fma(cs, c64, -sn * s64);
        const double nsn = fma(sn, c64,  cs * s64);
        cs = ncs; sn = nsn;
    }

    // wave argmax reduction per head
    #pragma unroll
    for (int h = 0; h < HH; h++) {
        for (int off = 32; off >= 1; off >>= 1) {
            const double ob = __shfl_down(best[h], off, 64);
            const float  od = __shfl_down(bd[h],  off, 64);
            if (ob > best[h]) { best[h] = ob; bd[h] = od; }
        }
        bd[h] = __shfl(bd[h], 0, 64);   // broadcast winner payload
    }

    // ---- epilogue (f32, mirrors reference element-wise math) ----
    const float dt_f  = (float)idb[t];
    const float quadf = 0.5f * epsf;
    const float x0t_f = Cf - quadf * dt_f * dt_f;

    const float a0 = bd[0], a1 = bd[1], a2 = bd[2], a3 = bd[3], a4 = bd[4];
    const float upd0 = o_w[0] * a0 + o_w[1] * a1 + o_w[2] * a2;
    const float upd1 = o_w[3] * a0 + o_w[4] * a3 + o_w[5] * a4;

    const float x0 = x0t_f + upd0;
    const float x1 = dt_f + upd1;

    const float wa = w1_abc[0], wb = w1_abc[1], wc = w1_abc[2];
    const float h0 = fmaxf(wa * x0 + (Cf - 8.0f), 0.0f);
    const float h1 = fmaxf(wa * x0 + (Cf - 9.0f), 0.0f);
    const float h2 = fmaxf(wb * x0 + wc * x1 + (2.0f * Cf - 188.0f), 0.0f);
    const float h3 = fmaxf(wb * x0 + wc * x1 + (2.0f * Cf - 189.0f), 0.0f);

    const float s1 = w2_s[0], s10 = w2_s[1];
    const float x1f = x1 + s1 * h0 - s1 * h1 - s10 * h2 + s10 * h3;

    const float y0 = x0 * (1.0f / Cf);
    const float y1 = x1f * epsf;

    if (lane < VV) {
        const float fv = (float)lane;
        const float e0 = Cf - quadf * fv * fv;
        out[(size_t)(b * TT + t) * VV + lane] = y0 * e0 + y1 * fv;
    }
}

extern "C" void kernel_launch(void* const* d_in, const int* in_sizes, int n_in,
                              void* d_out, int out_size, void* d_ws, size_t ws_size,
                              hipStream_t stream) {
    (void)in_sizes; (void)n_in; (void)d_ws; (void)ws_size; (void)out_size;
    const int*   ids = (const int*)  d_in[0];
    const float* o_w = (const float*)d_in[1];
    const float* w1  = (const float*)d_in[2];
    const float* w2  = (const float*)d_in[3];
    const float* Cc  = (const float*)d_in[4];
    const float* ee  = (const float*)d_in[5];
    const float* qq  = (const float*)d_in[6];
    const float* ro  = (const float*)d_in[7];
    float* out = (float*)d_out;

    // one wave per (b,t): B*T/4 blocks of 4 waves
    dim3 grid(BB * TT / 4);
    dim3 block(256);
    hipLaunchKernelGGL(transformer_kernel, grid, block, 0, stream,
                       ids, o_w, w1, w2, Cc, ee, qq, ro, out);
}

// Round 3
// 80.307 us; speedup vs baseline: 1.6488x; 1.6488x over previous
//
#include <hip/hip_runtime.h>
#include <math.h>

#define BB 8
#define TT 2048
#define VV 10
#define HH 5
#define NB 512            // angle buckets (width 2*pi/512 = 0.012272 rad)
#define TPB 128           // threads per block (2 waves)
#define ROWS_PER_BLOCK 128

// One workgroup per 128 (b,t) rows (single b per WG). Phase 1: build a
// bucket-sorted LUT over the 2048 key positions: angle(s) = s mod 2pi,
// entry = (x0[b,s]*cos s, x0[b,s]*sin s, s|d<<12). Phase 2: each thread
// resolves one (b,t) row: for each of 5 heads, scan +-1 bucket around the
// query angle (t - off_h) mod 2pi; provably contains the f64 argmax of
//   f(s) = x0[s]*cos(t-off_h-s) - (1e4/K)*[s>t],  K = qk^2/sqrt(2)*x0[t]
// (winner is within 7.8e-3 rad of the query; window covers 12.3e-3).
// Softmax of the ~4.6e10-magnitude scores is one-hot => att_h = d[argmax].
__global__ __launch_bounds__(TPB) void transformer_kernel(
    const int* __restrict__ ids,
    const float* __restrict__ o_w,
    const float* __restrict__ w1_abc,
    const float* __restrict__ w2_s,
    const float* __restrict__ embed_const,
    const float* __restrict__ decode_eps,
    const float* __restrict__ qk_scale,
    const float* __restrict__ rope_offsets,
    float* __restrict__ out)
{
    __shared__ double2 ent_cd[TT];          // (x0*cos s, x0*sin s) bucket-sorted
    __shared__ unsigned short ent_sd[TT];   // s | (d<<12)
    __shared__ int start[NB + 1];
    __shared__ int cnt[NB];
    __shared__ int cursor[NB];
    __shared__ double coff[HH], soff[HH], offd[HH];

    const int tid = threadIdx.x;
    const int row0 = blockIdx.x * ROWS_PER_BLOCK;
    const int b = row0 >> 11;               // 16 WGs per batch

    const double C    = (double)embed_const[0];
    const double eps  = (double)decode_eps[0];
    const double quad = 0.5 * eps;
    const double qkd  = (double)qk_scale[0];

    const double TWO_PI  = 6.283185307179586476925286766559;
    const double INV_2PI = 0.15915494309189533576888376337251;
    const double BSCALE  = (double)NB * INV_2PI;

    for (int j = tid; j < NB; j += TPB) cnt[j] = 0;
    if (tid < HH) {
        double so, co;
        const double od = (double)rope_offsets[tid];
        sincos(od, &so, &co);
        coff[tid] = co; soff[tid] = so; offd[tid] = od;
    }
    __syncthreads();

    const int* idb = ids + b * TT;

    // rotation constants for stepping s by TPB rad
    double sstep, cstep;
    sincos((double)TPB, &sstep, &cstep);

    // ---- pass 1: count bucket occupancy ----
    {
        double sn, cs;
        sincos((double)tid, &sn, &cs);
        for (int k = 0; k < TT / TPB; k++) {
            const int s = tid + k * TPB;
            const double sd = (double)s;
            const double phi = sd - floor(sd * INV_2PI) * TWO_PI;
            int j = (int)(phi * BSCALE);
            j = j < 0 ? 0 : (j > NB - 1 ? NB - 1 : j);
            atomicAdd(&cnt[j], 1);
            const double ncs = cs * cstep - sn * sstep;
            const double nsn = sn * cstep + cs * sstep;
            cs = ncs; sn = nsn;
        }
    }
    __syncthreads();

    // ---- exclusive scan over 512 buckets (wave 0) ----
    if (tid < 64) {
        const int base = tid * 8;
        int local[8]; int sum = 0;
        #pragma unroll
        for (int j2 = 0; j2 < 8; j2++) { local[j2] = sum; sum += cnt[base + j2]; }
        int inc = sum;
        for (int off = 1; off < 64; off <<= 1) {
            const int v = __shfl_up(inc, off, 64);
            if (tid >= off) inc += v;
        }
        const int excl = inc - sum;
        #pragma unroll
        for (int j2 = 0; j2 < 8; j2++) {
            const int st = excl + local[j2];
            start[base + j2] = st; cursor[base + j2] = st;
        }
        if (tid == 63) start[NB] = excl + sum;   // = 2048
    }
    __syncthreads();

    // ---- pass 2: scatter entries ----
    {
        double sn, cs;
        sincos((double)tid, &sn, &cs);
        for (int k = 0; k < TT / TPB; k++) {
            const int s = tid + k * TPB;
            const int d = idb[s];
            const double dd = (double)d;
            const double x0s = C - quad * dd * dd;
            const double sd = (double)s;
            const double phi = sd - floor(sd * INV_2PI) * TWO_PI;
            int j = (int)(phi * BSCALE);
            j = j < 0 ? 0 : (j > NB - 1 ? NB - 1 : j);
            const int pos = atomicAdd(&cursor[j], 1);
            ent_cd[pos] = make_double2(x0s * cs, x0s * sn);
            ent_sd[pos] = (unsigned short)(s | (d << 12));
            const double ncs = cs * cstep - sn * sstep;
            const double nsn = sn * cstep + cs * sstep;
            cs = ncs; sn = nsn;
        }
    }
    __syncthreads();

    // ---- phase 2: one row (b,t) per thread ----
    const int row = row0 + tid;
    const int t = row & 2047;

    const int dt_i = idb[t];
    const double dtd = (double)dt_i;
    const double x0t = C - quad * dtd * dtd;
    const double K = qkd * qkd * 0.70710678118654752440 * x0t;
    const double m = 10000.0 / K;

    double st_, ct_;
    sincos((double)t, &st_, &ct_);

    float bd[HH];
    #pragma unroll
    for (int h = 0; h < HH; h++) {
        // query direction cos/sin(t - off_h), product form matching reference
        const double cq = coff[h] * ct_ + soff[h] * st_;
        const double sq = coff[h] * st_ - soff[h] * ct_;
        const double a = (double)t - offd[h];
        const double phi = a - floor(a * INV_2PI) * TWO_PI;
        int jq = (int)(phi * BSCALE);
        jq = jq < 0 ? 0 : (jq > NB - 1 ? NB - 1 : jq);

        double best = -1e300; float bdd = 0.0f;
        #pragma unroll
        for (int dj = -1; dj <= 1; dj++) {
            const int j = (jq + dj) & (NB - 1);
            const int e1 = start[j + 1];
            for (int e = start[j]; e < e1; e++) {
                const double2 cd = ent_cd[e];
                const int v = ent_sd[e];
                const int s_e = v & 0xFFF;
                double sc = cq * cd.x + sq * cd.y;
                if (s_e > t) sc -= m;
                if (sc > best) { best = sc; bdd = (float)(v >> 12); }
            }
        }
        bd[h] = bdd;
    }

    // ---- epilogue (f32, mirrors reference element-wise math) ----
    const float Cf = embed_const[0];
    const float epsf = decode_eps[0];
    const float quadf = 0.5f * epsf;
    const float dt_f = (float)dt_i;
    const float x0t_f = Cf - quadf * dt_f * dt_f;

    const float a0 = bd[0], a1 = bd[1], a2 = bd[2], a3 = bd[3], a4 = bd[4];
    const float upd0 = o_w[0] * a0 + o_w[1] * a1 + o_w[2] * a2;
    const float upd1 = o_w[3] * a0 + o_w[4] * a3 + o_w[5] * a4;

    const float x0 = x0t_f + upd0;
    const float x1 = dt_f + upd1;

    const float wa = w1_abc[0], wb = w1_abc[1], wc = w1_abc[2];
    const float h0 = fmaxf(wa * x0 + (Cf - 8.0f), 0.0f);
    const float h1 = fmaxf(wa * x0 + (Cf - 9.0f), 0.0f);
    const float h2 = fmaxf(wb * x0 + wc * x1 + (2.0f * Cf - 188.0f), 0.0f);
    const float h3 = fmaxf(wb * x0 + wc * x1 + (2.0f * Cf - 189.0f), 0.0f);

    const float s1 = w2_s[0], s10 = w2_s[1];
    const float x1f = x1 + s1 * h0 - s1 * h1 - s10 * h2 + s10 * h3;

    const float y0 = x0 * (1.0f / Cf);
    const float y1 = x1f * epsf;

    #pragma unroll
    for (int v = 0; v < VV; v++) {
        const float fv = (float)v;
        const float e0 = Cf - quadf * fv * fv;
        out[(size_t)row * VV + v] = y0 * e0 + y1 * fv;
    }
}

extern "C" void kernel_launch(void* const* d_in, const int* in_sizes, int n_in,
                              void* d_out, int out_size, void* d_ws, size_t ws_size,
                              hipStream_t stream) {
    (void)in_sizes; (void)n_in; (void)d_ws; (void)ws_size; (void)out_size;
    const int*   ids = (const int*)  d_in[0];
    const float* o_w = (const float*)d_in[1];
    const float* w1  = (const float*)d_in[2];
    const float* w2  = (const float*)d_in[3];
    const float* Cc  = (const float*)d_in[4];
    const float* ee  = (const float*)d_in[5];
    const float* qq  = (const float*)d_in[6];
    const float* ro  = (const float*)d_in[7];
    float* out = (float*)d_out;

    dim3 grid(BB * TT / ROWS_PER_BLOCK);   // 128 blocks
    dim3 block(TPB);                       // 128 threads
    hipLaunchKernelGGL(transformer_kernel, grid, block, 0, stream,
                       ids, o_w, w1, w2, Cc, ee, qq, ro, out);
}

// Round 4
// 74.640 us; speedup vs baseline: 1.7740x; 1.0759x over previous
//
#include <hip/hip_runtime.h>
#include <math.h>

#define BB 8
#define TT 2048
#define VV 10
#define HH 5
#define CAP 64            // candidate-table capacity per head (expected ~14)
#define THR 0.011         // residue window; winner provably within 7.63e-3

// Stage A: per-head candidate tables in offset space.
// score(b,h,t,s) = K * x0[b,s] * cos((s-t)+off_h) - 1e4*[s>t],
//   K = qk^2/sqrt(2) * x0[b,t]  (~4.6e7), x0 in [999.9798, 1000].
// Softmax over these is one-hot => att_h = d[argmax]. The winner's angle
// residue r = (o+off_h) mod 2pi obeys  x0min*(1-cos r) <= pen_bestavail
// (max circle gap 8.3e-3 => 8.7e-3) + x0 spread (0.0202) + mask (2.2e-4)
// => |r| <= 7.63e-3 < THR. So per head the candidate offsets o=s-t form a
// fixed ~14-entry subset of [-2047,2047], independent of t. Stage B scans
// only those.
__global__ __launch_bounds__(256) void build_tables(
    const float* __restrict__ rope_offsets,
    int* __restrict__ cnt_g, int* __restrict__ o_g, double* __restrict__ cr_g)
{
    __shared__ int cnt;
    __shared__ int o_l[CAP];
    __shared__ double cr_l[CAP];
    const int h = blockIdx.x;
    if (threadIdx.x == 0) cnt = 0;
    __syncthreads();

    const double TWO_PI  = 6.283185307179586476925286766559;
    const double INV_2PI = 0.15915494309189533576888376337251;
    const double off = (double)rope_offsets[h];

    for (int i = threadIdx.x; i < 2 * TT - 1; i += 256) {
        const int o = i - (TT - 1);
        const double a = (double)o + off;
        const double n = rint(a * INV_2PI);
        const double r = fma(-n, TWO_PI, a);
        if (fabs(r) <= THR) {
            const int p = atomicAdd(&cnt, 1) & (CAP - 1);
            o_l[p] = o;
            cr_l[p] = cos(r);
        }
    }
    __syncthreads();
    if (threadIdx.x == 0) cnt_g[h] = (cnt < CAP) ? cnt : CAP;
    if (threadIdx.x < CAP && threadIdx.x < cnt) {
        o_g[h * CAP + threadIdx.x]  = o_l[threadIdx.x];
        cr_g[h * CAP + threadIdx.x] = cr_l[threadIdx.x];
    }
}

// Stage B: one thread per (row, head). Block = 320 threads: wave w handles
// head w for 64 consecutive rows (uniform head per wave -> uniform loop
// count, no divergence). Head results exchanged via LDS; wave 0 epilogue.
__global__ __launch_bounds__(320) void attn_rows(
    const int* __restrict__ ids,
    const float* __restrict__ o_w,
    const float* __restrict__ w1_abc,
    const float* __restrict__ w2_s,
    const float* __restrict__ embed_const,
    const float* __restrict__ decode_eps,
    const float* __restrict__ qk_scale,
    const int* __restrict__ cnt_g,
    const int* __restrict__ o_g,
    const double* __restrict__ cr_g,
    float* __restrict__ out)
{
    __shared__ float bdL[64][HH];
    __shared__ int oL[HH][CAP];
    __shared__ double crL[HH][CAP];
    __shared__ int cntL[HH];

    const int tid = threadIdx.x;
    if (tid < HH) cntL[tid] = cnt_g[tid];
    for (int i = tid; i < HH * CAP; i += 320) {
        oL[i / CAP][i & (CAP - 1)]  = o_g[i];
        crL[i / CAP][i & (CAP - 1)] = cr_g[i];
    }
    __syncthreads();

    const int h = tid >> 6;          // 0..4, wave-uniform
    const int r = tid & 63;
    const int row = blockIdx.x * 64 + r;
    const int b = row >> 11;         // 32 blocks per batch
    const int t = row & 2047;
    const int* idb = ids + b * TT;

    const double C    = (double)embed_const[0];
    const double quad = 0.5 * (double)decode_eps[0];
    const double qkd  = (double)qk_scale[0];

    const int dt_i = idb[t];
    const double dtd = (double)dt_i;
    const double x0t = C - quad * dtd * dtd;
    const double K = qkd * qkd * 0.70710678118654752440 * x0t;

    const int cnt = cntL[h];
    double best = -1e300;
    float bdd = 0.0f;
    for (int i = 0; i < cnt; i++) {
        const int o = oL[h][i];              // LDS broadcast (uniform addr)
        const double cr = crL[h][i];
        const int s = t + o;
        const bool valid = ((unsigned)s < (unsigned)TT);
        const double dd = (double)idb[valid ? s : 0];
        const double x0s = C - quad * dd * dd;
        double sc = K * x0s * cr;
        if (o > 0) sc -= 10000.0;            // mask (s>t <=> o>0)
        if (valid && sc > best) { best = sc; bdd = (float)dd; }
    }
    bdL[r][h] = bdd;
    __syncthreads();

    // ---- epilogue (f32, mirrors reference element-wise math) ----
    if (tid < 64) {
        const int row_e = blockIdx.x * 64 + tid;
        const int t_e = row_e & 2047;
        const int dte = idb[t_e];

        const float Cf = embed_const[0];
        const float epsf = decode_eps[0];
        const float quadf = 0.5f * epsf;
        const float dt_f = (float)dte;
        const float x0t_f = Cf - quadf * dt_f * dt_f;

        const float a0 = bdL[tid][0], a1 = bdL[tid][1], a2 = bdL[tid][2];
        const float a3 = bdL[tid][3], a4 = bdL[tid][4];
        const float upd0 = o_w[0] * a0 + o_w[1] * a1 + o_w[2] * a2;
        const float upd1 = o_w[3] * a0 + o_w[4] * a3 + o_w[5] * a4;

        const float x0 = x0t_f + upd0;
        const float x1 = dt_f + upd1;

        const float wa = w1_abc[0], wb = w1_abc[1], wc = w1_abc[2];
        const float h0 = fmaxf(wa * x0 + (Cf - 8.0f), 0.0f);
        const float h1 = fmaxf(wa * x0 + (Cf - 9.0f), 0.0f);
        const float h2 = fmaxf(wb * x0 + wc * x1 + (2.0f * Cf - 188.0f), 0.0f);
        const float h3 = fmaxf(wb * x0 + wc * x1 + (2.0f * Cf - 189.0f), 0.0f);

        const float s1 = w2_s[0], s10 = w2_s[1];
        const float x1f = x1 + s1 * h0 - s1 * h1 - s10 * h2 + s10 * h3;

        const float y0 = x0 * (1.0f / Cf);
        const float y1 = x1f * epsf;

        #pragma unroll
        for (int v = 0; v < VV; v++) {
            const float fv = (float)v;
            const float e0 = Cf - quadf * fv * fv;
            out[(size_t)row_e * VV + v] = y0 * e0 + y1 * fv;
        }
    }
}

extern "C" void kernel_launch(void* const* d_in, const int* in_sizes, int n_in,
                              void* d_out, int out_size, void* d_ws, size_t ws_size,
                              hipStream_t stream) {
    (void)in_sizes; (void)n_in; (void)ws_size; (void)out_size;
    const int*   ids = (const int*)  d_in[0];
    const float* o_w = (const float*)d_in[1];
    const float* w1  = (const float*)d_in[2];
    const float* w2  = (const float*)d_in[3];
    const float* Cc  = (const float*)d_in[4];
    const float* ee  = (const float*)d_in[5];
    const float* qq  = (const float*)d_in[6];
    const float* ro  = (const float*)d_in[7];
    float* out = (float*)d_out;

    char* ws = (char*)d_ws;
    int*    cnt_g = (int*)ws;                      // 5 ints
    int*    o_g   = (int*)(ws + 256);              // 5*64 ints
    double* cr_g  = (double*)(ws + 2048);          // 5*64 doubles

    hipLaunchKernelGGL(build_tables, dim3(HH), dim3(256), 0, stream,
                       ro, cnt_g, o_g, cr_g);
    hipLaunchKernelGGL(attn_rows, dim3(BB * TT / 64), dim3(320), 0, stream,
                       ids, o_w, w1, w2, Cc, ee, qq, cnt_g, o_g, cr_g, out);
}